// Round 1
// baseline (122.735 us; speedup 1.0000x reference)
//
#include <hip/hip_runtime.h>

#define NB 16
#define SS 2048
#define DD 64

typedef __attribute__((ext_vector_type(8))) short short8;
typedef __attribute__((ext_vector_type(4))) float f32x4;

// SCALE * log2(e), folded so softmax exp is one v_mul + one v_exp
#define SCL2E 0.18033688011112042f

// round-to-nearest-even f32 -> bf16 (as raw short)
__device__ __forceinline__ short f2bf(float f) {
  union { float f; unsigned u; } v; v.f = f;
  unsigned r = (v.u + 0x7fffu + ((v.u >> 16) & 1u)) >> 16;
  return (short)r;
}

// packed RNE f32x2 -> bf16x2 (no builtin on gfx950; guide T12)
__device__ __forceinline__ unsigned cvtpk_bf16(float lo, float hi) {
  unsigned r;
  asm("v_cvt_pk_bf16_f32 %0, %1, %2" : "=v"(r) : "v"(lo), "v"(hi));
  return r;
}

__device__ __forceinline__ short8 load_a_frag_f32(const float* p) {
  float4 u = *(const float4*)p;
  float4 w = *(const float4*)(p + 4);
  short8 r;
  r[0] = f2bf(u.x); r[1] = f2bf(u.y); r[2] = f2bf(u.z); r[3] = f2bf(u.w);
  r[4] = f2bf(w.x); r[5] = f2bf(w.y); r[6] = f2bf(w.z); r[7] = f2bf(w.w);
  return r;
}

// ---------------------------------------------------------------------------
// One-shot W transpose: Wt[m][n][k] = W[k][n] as bf16, k-contiguous, so proj
// can load MFMA A-frags (8 consecutive k per lane) straight from global.
// ---------------------------------------------------------------------------
__global__ __launch_bounds__(256) void wprep_kernel(
    const float* __restrict__ Wq, const float* __restrict__ Wk,
    const float* __restrict__ Wv, ushort* __restrict__ Wt)
{
  const float* Ws[3] = {Wq, Wk, Wv};
  const int m = blockIdx.x;
  const float* src = Ws[m];
  ushort* dst = Wt + m * 4096;
  const int t = threadIdx.x;
#pragma unroll
  for (int i = 0; i < 4; ++i) {
    int idx = i * 1024 + t * 4;
    int k = idx >> 6, n0 = idx & 63;
    float4 w4 = *(const float4*)(src + idx);
    dst[(n0 + 0) * 64 + k] = (ushort)f2bf(w4.x);
    dst[(n0 + 1) * 64 + k] = (ushort)f2bf(w4.y);
    dst[(n0 + 2) * 64 + k] = (ushort)f2bf(w4.z);
    dst[(n0 + 3) * 64 + k] = (ushort)f2bf(w4.w);
  }
}

// ---------------------------------------------------------------------------
// QKV projection v2: no per-block W staging (Wt preloaded, L1-resident).
// Swapped orientation: mfma(A=Wt, B=x) -> lane(l15,quad) holds
// out[row=g(l15)][n = nt*16 + quad*4 + r] -> 4 consecutive cols -> one 8B
// packed store per nt. V goes to LDS (b64 writes) for the vT transpose.
// ---------------------------------------------------------------------------
__global__ __launch_bounds__(256) void proj_kernel(
    const float* __restrict__ x, const ushort* __restrict__ Wt,
    const float* __restrict__ bq, const float* __restrict__ bk,
    const float* __restrict__ bv,
    ushort* __restrict__ qo, ushort* __restrict__ ko, ushort* __restrict__ vT)
{
  __shared__ __align__(16) ushort Vs[64][68];
  const int t = threadIdx.x;
  const int lane = t & 63, w = t >> 6;
  const int l15 = lane & 15, quad = lane >> 4;
  const int g = blockIdx.x * 64 + w * 16 + l15;
  // B-frags: x row g, dims quad*8.. and 32+quad*8..
  short8 b0 = load_a_frag_f32(x + (size_t)g * 64 + quad * 8);
  short8 b1 = load_a_frag_f32(x + (size_t)g * 64 + 32 + quad * 8);
  const int lrow = w * 16 + l15;

#pragma unroll
  for (int m = 0; m < 3; ++m) {
    const float* bp = (m == 0 ? bq : (m == 1 ? bk : bv));
    const ushort* wm = Wt + m * 4096;
#pragma unroll
    for (int nt = 0; nt < 4; ++nt) {
      const ushort* ap = wm + (nt * 16 + l15) * 64 + quad * 8;
      short8 a0 = *(const short8*)ap;
      short8 a1 = *(const short8*)(ap + 32);
      f32x4 acc = {0.f, 0.f, 0.f, 0.f};
      acc = __builtin_amdgcn_mfma_f32_16x16x32_bf16(a0, b0, acc, 0, 0, 0);
      acc = __builtin_amdgcn_mfma_f32_16x16x32_bf16(a1, b1, acc, 0, 0, 0);
      float4 bb = *(const float4*)(bp + nt * 16 + quad * 4);
      unsigned p0 = cvtpk_bf16(acc[0] + bb.x, acc[1] + bb.y);
      unsigned p1 = cvtpk_bf16(acc[2] + bb.z, acc[3] + bb.w);
      uint2 pk; pk.x = p0; pk.y = p1;
      if (m == 0) {
        *(uint2*)(qo + (size_t)g * 64 + nt * 16 + quad * 4) = pk;
      } else if (m == 1) {
        *(uint2*)(ko + (size_t)g * 64 + nt * 16 + quad * 4) = pk;
      } else {
        *(uint2*)&Vs[lrow][nt * 16 + quad * 4] = pk;
      }
    }
  }
  __syncthreads();
  {
    const int batch = blockIdx.x >> 5;
    const int s0 = (blockIdx.x & 31) * 64;
    const int d = t >> 2, j0 = (t & 3) * 16;
    ushort tmp[16];
#pragma unroll
    for (int j = 0; j < 16; ++j) tmp[j] = Vs[j0 + j][d];
    ushort* dst = vT + (size_t)batch * DD * SS + (size_t)d * SS + s0 + j0;
    ((int4*)dst)[0] = ((int4*)tmp)[0];
    ((int4*)dst)[1] = ((int4*)tmp)[1];
  }
}

// ---------------------------------------------------------------------------
// In-register P redistribution (T12 adapted to 16x16 frags).
// Swapped QK gives lane(l15=q, quad) the P values for keys ct*16+quad*4+r.
// PV A-frag needs lane(l15=q, quad) to hold keys quad*8+j (j=0..7).
// Key k decomposes as: ct = k>>4 selects the pack pair (A=first ct, B=second),
// src quad s = (k>>2)&3, pack half h = (k&3)>>1. For target quad t, word w
// (keys t*8+2w): ct = t>>1, s = (2t + (w>>1))&3, h = w&1.
// After shfl_xor(32): Lo = [A_lo|B_lo], Hi = [A_hi|B_hi]; then
// word(grp0,h) = odd ? xor16(Hi_h) : Lo_h ; word(grp1,h) = odd ? Hi_h : xor16(Lo_h).
// ---------------------------------------------------------------------------
__device__ __forceinline__ short8 build_pa(unsigned A0, unsigned A1,
                                           unsigned B0, unsigned B1, int quad) {
  int xA0 = __shfl_xor((int)A0, 32);
  int xA1 = __shfl_xor((int)A1, 32);
  int xB0 = __shfl_xor((int)B0, 32);
  int xB1 = __shfl_xor((int)B1, 32);
  const bool hi = quad >= 2;
  const bool odd = quad & 1;
  int Lo0 = hi ? xB0 : (int)A0;   // [A_lo | B_lo]
  int Lo1 = hi ? xB1 : (int)A1;
  int Hi0 = hi ? (int)B0 : xA0;   // [A_hi | B_hi]
  int Hi1 = hi ? (int)B1 : xA1;
  int xLo0 = __shfl_xor(Lo0, 16);
  int xLo1 = __shfl_xor(Lo1, 16);
  int xHi0 = __shfl_xor(Hi0, 16);
  int xHi1 = __shfl_xor(Hi1, 16);
  int4 wv;
  wv.x = odd ? xHi0 : Lo0;   // keys quad*8 + 0,1
  wv.y = odd ? xHi1 : Lo1;   // keys quad*8 + 2,3
  wv.z = odd ? Hi0 : xLo0;   // keys quad*8 + 4,5
  wv.w = odd ? Hi1 : xLo1;   // keys quad*8 + 6,7
  return *(short8*)&wv;
}

// exp + in-register P build + PV for one 16-query half. MASKED compile-time.
// c[ct][r] = S[key = kb + ct*16 + quad*4 + r][q = qabs(lane)]
template<bool MASKED>
__device__ __forceinline__ void attn_half(
    const f32x4 (&c)[4], float& l_acc, f32x4 (&acc)[4],
    const short8 (&vf0)[4], const short8 (&vf1)[4],
    int keybase, int qabs, int quad)
{
  unsigned pk[4][2];
#pragma unroll
  for (int ct = 0; ct < 4; ++ct) {
    float pe[4];
#pragma unroll
    for (int r = 0; r < 4; ++r) {
      float p = __builtin_amdgcn_exp2f(c[ct][r] * SCL2E);
      if (MASKED && (keybase + ct * 16 + quad * 4 + r > qabs)) p = 0.f;
      pe[r] = p;
      l_acc += p;
    }
    pk[ct][0] = cvtpk_bf16(pe[0], pe[1]);
    pk[ct][1] = cvtpk_bf16(pe[2], pe[3]);
  }
  short8 pa0 = build_pa(pk[0][0], pk[0][1], pk[1][0], pk[1][1], quad);
  short8 pa1 = build_pa(pk[2][0], pk[2][1], pk[3][0], pk[3][1], quad);
  __builtin_amdgcn_s_setprio(1);
#pragma unroll
  for (int nt = 0; nt < 4; ++nt) {
    acc[nt] = __builtin_amdgcn_mfma_f32_16x16x32_bf16(pa0, vf0[nt], acc[nt], 0, 0, 0);
    acc[nt] = __builtin_amdgcn_mfma_f32_16x16x32_bf16(pa1, vf1[nt], acc[nt], 0, 0, 0);
  }
  __builtin_amdgcn_s_setprio(0);
}

// ---------------------------------------------------------------------------
// Flash causal attention: 32 queries/block, 4 waves key-split, swapped QK
// (Sᵀ) so softmax+P stay fully in registers (no LDS P round-trip).
// ---------------------------------------------------------------------------
__global__ __launch_bounds__(256, 3) void attn_kernel(
    const ushort* __restrict__ qg, const ushort* __restrict__ kg,
    const ushort* __restrict__ vT, float* __restrict__ out)
{
  __shared__ __align__(16) float accW[4][32][68];
  __shared__ float lW[4][32];

  const int t = threadIdx.x, bid = blockIdx.x;
  const int batch = (bid & 7) * 2 + ((bid >> 3) & 1);  // 2 batches per XCD
  const int qt = 63 - (bid >> 4);                      // heavy blocks first
  const int q0 = qt * 32;
  const int lane = t & 63, w = t >> 6;
  const int l15 = lane & 15, quad = lane >> 4;
  const size_t bbase = (size_t)batch * SS * DD;

  // Q fragments (B operand now): lane l15 = query row
  const ushort* qp = qg + bbase + (size_t)(q0 + l15) * 64 + quad * 8;
  short8 a0 = *(const short8*)qp;
  short8 a1 = *(const short8*)(qp + 32);
  short8 a2 = *(const short8*)(qp + 16 * 64);
  short8 a3 = *(const short8*)(qp + 16 * 64 + 32);

  f32x4 acc0[4], acc1[4];
  float l0 = 0.f, l1 = 0.f;
#pragma unroll
  for (int nt = 0; nt < 4; ++nt) {
    acc0[nt] = (f32x4){0.f, 0.f, 0.f, 0.f};
    acc1[nt] = (f32x4){0.f, 0.f, 0.f, 0.f};
  }

  const int ktotal = ((q0 + 31) >> 6) + 1;   // 64-key tiles
  const ushort* kp0 = kg + bbase + (size_t)(w * 64 + l15) * 64 + quad * 8;
  const ushort* kp1 = kp0 + 2048;            // +32 key rows
  const ushort* vp0 = vT + bbase + (size_t)(l15) * SS + w * 64 + quad * 8;
  const ushort* vp1 = vp0 + 16 * SS;
  const ushort* vp2 = vp0 + 32 * SS;
  const ushort* vp3 = vp0 + 48 * SS;

  const int qabs0 = q0 + l15, qabs1 = q0 + 16 + l15;

  for (int kt = w; kt < ktotal; kt += 4) {
    short8 kf0[4], kf1[4], vf0[4], vf1[4];
    kf0[0] = *(const short8*)(kp0);
    kf1[0] = *(const short8*)(kp0 + 32);
    kf0[1] = *(const short8*)(kp0 + 1024);
    kf1[1] = *(const short8*)(kp0 + 1056);
    kf0[2] = *(const short8*)(kp1);
    kf1[2] = *(const short8*)(kp1 + 32);
    kf0[3] = *(const short8*)(kp1 + 1024);
    kf1[3] = *(const short8*)(kp1 + 1056);
    vf0[0] = *(const short8*)(vp0); vf1[0] = *(const short8*)(vp0 + 32);
    vf0[1] = *(const short8*)(vp1); vf1[1] = *(const short8*)(vp1 + 32);
    vf0[2] = *(const short8*)(vp2); vf1[2] = *(const short8*)(vp2 + 32);
    vf0[3] = *(const short8*)(vp3); vf1[3] = *(const short8*)(vp3 + 32);

    // Swapped QK: c = mfma(K, Q) -> Sᵀ tile; lane l15 = query.
    f32x4 c0[4], c1[4];
    __builtin_amdgcn_s_setprio(1);
#pragma unroll
    for (int ct = 0; ct < 4; ++ct) {
      f32x4 z = {0.f, 0.f, 0.f, 0.f};
      c0[ct] = __builtin_amdgcn_mfma_f32_16x16x32_bf16(kf0[ct], a0, z, 0, 0, 0);
      c0[ct] = __builtin_amdgcn_mfma_f32_16x16x32_bf16(kf1[ct], a1, c0[ct], 0, 0, 0);
      c1[ct] = __builtin_amdgcn_mfma_f32_16x16x32_bf16(kf0[ct], a2, z, 0, 0, 0);
      c1[ct] = __builtin_amdgcn_mfma_f32_16x16x32_bf16(kf1[ct], a3, c1[ct], 0, 0, 0);
    }
    __builtin_amdgcn_s_setprio(0);

    const int kb = kt * 64;
    if (kt == ktotal - 1) {
      attn_half<true >(c0, l0, acc0, vf0, vf1, kb, qabs0, quad);
      attn_half<true >(c1, l1, acc1, vf0, vf1, kb, qabs1, quad);
    } else {
      attn_half<false>(c0, l0, acc0, vf0, vf1, kb, qabs0, quad);
      attn_half<false>(c1, l1, acc1, vf0, vf1, kb, qabs1, quad);
    }
    kp0 += 16384; kp1 += 16384;
    vp0 += 256; vp1 += 256; vp2 += 256; vp3 += 256;
  }

  // l is per-lane (q = l15); sum across the 4 quads holding different keys
  l0 += __shfl_xor(l0, 16); l0 += __shfl_xor(l0, 32);
  l1 += __shfl_xor(l1, 16); l1 += __shfl_xor(l1, 32);

#pragma unroll
  for (int r = 0; r < 4; ++r)
#pragma unroll
    for (int nt = 0; nt < 4; ++nt) {
      accW[w][quad * 4 + r][nt * 16 + l15] = acc0[nt][r];
      accW[w][16 + quad * 4 + r][nt * 16 + l15] = acc1[nt][r];
    }
  if (lane < 16) {
    lW[w][lane] = l0;
    lW[w][16 + lane] = l1;
  }
  __syncthreads();

  // combine: plain sums, 8 floats per thread, coalesced
  {
    const int row = t >> 3, col0 = (t & 7) * 8;
    float den = lW[0][row] + lW[1][row] + lW[2][row] + lW[3][row];
    float iv = 1.0f / den;
    float4 oa = {0.f, 0.f, 0.f, 0.f}, ob = {0.f, 0.f, 0.f, 0.f};
#pragma unroll
    for (int ww = 0; ww < 4; ++ww) {
      float4 x0 = *(const float4*)&accW[ww][row][col0];
      float4 x1 = *(const float4*)&accW[ww][row][col0 + 4];
      oa.x += x0.x; oa.y += x0.y; oa.z += x0.z; oa.w += x0.w;
      ob.x += x1.x; ob.y += x1.y; ob.z += x1.z; ob.w += x1.w;
    }
    oa.x *= iv; oa.y *= iv; oa.z *= iv; oa.w *= iv;
    ob.x *= iv; ob.y *= iv; ob.z *= iv; ob.w *= iv;
    float* op = out + bbase + (size_t)(q0 + row) * 64 + col0;
    *(float4*)op = oa;
    *(float4*)(op + 4) = ob;
  }
}

extern "C" void kernel_launch(void* const* d_in, const int* in_sizes, int n_in,
                              void* d_out, int out_size, void* d_ws, size_t ws_size,
                              hipStream_t stream) {
  (void)in_sizes; (void)n_in; (void)out_size; (void)ws_size;
  const float* x  = (const float*)d_in[0];
  const float* Wq = (const float*)d_in[1];
  const float* bq = (const float*)d_in[2];
  const float* Wk = (const float*)d_in[3];
  const float* bk = (const float*)d_in[4];
  const float* Wv = (const float*)d_in[5];
  const float* bv = (const float*)d_in[6];
  float* out = (float*)d_out;

  ushort* qws = (ushort*)d_ws;                       // bf16 q: 4 MB
  ushort* kws = qws + (size_t)NB * SS * DD;          // bf16 k: 4 MB
  ushort* vws = kws + (size_t)NB * SS * DD;          // bf16 v^T: 4 MB
  ushort* wt  = vws + (size_t)NB * SS * DD;          // bf16 Wᵀ[3][64][64]: 24 KB

  wprep_kernel<<<dim3(3), dim3(256), 0, stream>>>(Wq, Wk, Wv, wt);
  proj_kernel<<<dim3(NB * SS / 64), dim3(256), 0, stream>>>(
      x, wt, bq, bk, bv, qws, kws, vws);
  attn_kernel<<<dim3(NB * (SS / 32)), dim3(256), 0, stream>>>(
      qws, kws, vws, out);
}